// Round 6
// baseline (722.112 us; speedup 1.0000x reference)
//
#include <hip/hip_runtime.h>

typedef unsigned short u16;
typedef __attribute__((ext_vector_type(4))) unsigned short u16x4;
typedef __attribute__((ext_vector_type(8))) short bf16x8;
typedef __attribute__((ext_vector_type(4))) float f32x4;

__device__ inline float bf2f(u16 u) {
  union { unsigned int i; float f; } v; v.i = ((unsigned int)u) << 16; return v.f;
}
__device__ inline u16 f2bf(float f) {
  union { float f; unsigned int i; } v; v.f = f;
  unsigned int r = v.i + 0x7fffu + ((v.i >> 16) & 1u);
  return (u16)(r >> 16);
}
// pack two f32 -> two bf16 in one u32 (round-half-up via +0x8000, then byte-perm)
__device__ inline unsigned int pack2bf(float lo, float hi) {
  union { float f; unsigned int i; } a, b; a.f = lo; b.f = hi;
  return __builtin_amdgcn_perm(b.i + 0x8000u, a.i + 0x8000u, 0x07060302u);
}

// async global->LDS, 16B per lane; LDS dest = wave-uniform base + lane*16 (m97/m104)
typedef const __attribute__((address_space(1))) unsigned int* gas_t;
typedef __attribute__((address_space(3))) unsigned int* las_t;
__device__ inline void gload_lds16(const u16* g, u16* l) {
  __builtin_amdgcn_global_load_lds((gas_t)(unsigned long long)(const void*)g,
                                   (las_t)(unsigned int)(unsigned long long)(void*)l,
                                   16, 0, 0);
}

// ---------------- fp32 -> bf16 convert (x) ----------------
__global__ __launch_bounds__(256) void cvt_bf16(const float* __restrict__ src,
                                                u16* __restrict__ dst, int n) {
  int i = (blockIdx.x * 256 + threadIdx.x) * 4;
  if (i >= n) return;
  float4 v = *(const float4*)(src + i);
  u16x4 o;
  o.x = f2bf(v.x); o.y = f2bf(v.y); o.z = f2bf(v.z); o.w = f2bf(v.w);
  *(u16x4*)(dst + i) = o;
}

// ---------------- bias concat (fp32): [bq|bk|bv] -> o[3n] ----------------
__global__ __launch_bounds__(256) void concat3(const float* __restrict__ a,
                                               const float* __restrict__ b,
                                               const float* __restrict__ c,
                                               float* __restrict__ o, int n) {
  int i = blockIdx.x * 256 + threadIdx.x;
  if (i >= n) return;
  o[i] = a[i]; o[n + i] = b[i]; o[2 * n + i] = c[i];
}

// ------------- transpose+convert: fp32 src [R][C] -> bf16 dst [C][R] -------
__global__ __launch_bounds__(256) void transpose_f32_bf16(const float* __restrict__ src,
                                                          u16* __restrict__ dst,
                                                          int R, int C) {
  __shared__ u16 tile[32][33];
  int tx = threadIdx.x & 31, ty = threadIdx.x >> 5;  // 32 x 8
  int c0 = blockIdx.x * 32, r0 = blockIdx.y * 32;
  #pragma unroll
  for (int i = ty; i < 32; i += 8)
    tile[i][tx] = f2bf(src[(size_t)(r0 + i) * C + c0 + tx]);
  __syncthreads();
  #pragma unroll
  for (int i = ty; i < 32; i += 8)
    dst[(size_t)(c0 + i) * R + r0 + tx] = tile[tx][i];
}

// ---- per-head V transpose from packed QKV: src row-stride RS, col offset CO ----
__global__ __launch_bounds__(256) void transpose_v(const u16* __restrict__ src,
                                                   u16* __restrict__ VT,
                                                   int B, int S, int H, int RS, int CO) {
  __shared__ u16 tile[32][33];
  int tx = threadIdx.x & 31, ty = threadIdx.x >> 5;
  int s0 = blockIdx.x * 32, d0 = blockIdx.y * 32;
  int bh = blockIdx.z;
  int b = bh / H, h = bh % H;
  #pragma unroll
  for (int i = ty; i < 32; i += 8)
    tile[i][tx] = src[(size_t)(b * S + s0 + i) * RS + CO + h * 64 + d0 + tx];
  __syncthreads();
  #pragma unroll
  for (int i = ty; i < 32; i += 8)
    VT[((size_t)bh * 64 + d0 + i) * S + s0 + tx] = tile[tx][i];
}

// ---------------- GEMM: C[M,N] = A[M,K] @ Bt[N,K]^T + bias, opt relu --------
__global__ __launch_bounds__(256) void gemm_bt(const u16* __restrict__ A,
                                               const u16* __restrict__ Bt,
                                               const float* __restrict__ bias,
                                               u16* __restrict__ C,
                                               int M, int N, int K, int relu) {
  __shared__ u16 As[128 * 32];
  __shared__ u16 Bs[128 * 32];
  const int tid = threadIdx.x;
  const int lane = tid & 63, wid = tid >> 6;
  const int lr = lane & 15, quad = lane >> 4;
  const int wm = (wid >> 1) * 64, wn = (wid & 1) * 64;
  const int m0 = blockIdx.y * 128, n0 = blockIdx.x * 128;
  const int lrow = lane >> 2;
  const int lcol = (lane & 3) * 8;

  f32x4 acc[4][4];
  const f32x4 zero = {0.f, 0.f, 0.f, 0.f};
  #pragma unroll
  for (int mt = 0; mt < 4; ++mt)
    #pragma unroll
    for (int nt = 0; nt < 4; ++nt) acc[mt][nt] = zero;

  for (int k0 = 0; k0 < K; k0 += 32) {
    #pragma unroll
    for (int it = 0; it < 2; ++it) {
      int rbase = wid * 32 + it * 16;
      gload_lds16(A + (size_t)(m0 + rbase + lrow) * K + k0 + lcol, &As[rbase * 32]);
      gload_lds16(Bt + (size_t)(n0 + rbase + lrow) * K + k0 + lcol, &Bs[rbase * 32]);
    }
    __syncthreads();
    bf16x8 af[4], bfr[4];
    #pragma unroll
    for (int mt = 0; mt < 4; ++mt)
      af[mt] = *(const bf16x8*)(&As[(wm + mt * 16 + lr) * 32 + quad * 8]);
    #pragma unroll
    for (int nt = 0; nt < 4; ++nt)
      bfr[nt] = *(const bf16x8*)(&Bs[(wn + nt * 16 + lr) * 32 + quad * 8]);
    #pragma unroll
    for (int mt = 0; mt < 4; ++mt)
      #pragma unroll
      for (int nt = 0; nt < 4; ++nt)
        acc[mt][nt] = __builtin_amdgcn_mfma_f32_16x16x32_bf16(af[mt], bfr[nt], acc[mt][nt], 0, 0, 0);
    __syncthreads();
  }

  #pragma unroll
  for (int nt = 0; nt < 4; ++nt) {
    int n = n0 + wn + nt * 16 + lr;
    float bv = bias[n];
    #pragma unroll
    for (int mt = 0; mt < 4; ++mt) {
      #pragma unroll
      for (int i = 0; i < 4; ++i) {
        int m = m0 + wm + mt * 16 + quad * 4 + i;
        float v = acc[mt][nt][i] + bv;
        if (relu) v = fmaxf(v, 0.f);
        C[(size_t)m * N + n] = f2bf(v);
      }
    }
  }
}

// ---------------- flash attention (S^T, 32 q-rows per wave) ----------------
// grid: (S/128, B*H); block 256 (4 waves); wave owns 32 q-rows (2 fragments).
__global__ __launch_bounds__(256) void flash_attn(const u16* __restrict__ Qp,
                                                  const u16* __restrict__ Kp,
                                                  const u16* __restrict__ VT,
                                                  const int* __restrict__ mask,
                                                  u16* __restrict__ ctx,
                                                  int B, int S, int H, int QSTR) {
  __shared__ u16 kt_lds[64 * 72];         // K tile [krow][dk]
  __shared__ u16 vt_lds[64 * 72];         // V^T tile [dk][krow]
  __shared__ u16 p_lds[4 * 32 * 72];      // per-wave P [q(32)][k]
  __shared__ float msk_lds[64];
  const int tid = threadIdx.x;
  const int lane = tid & 63, wid = tid >> 6;
  const int lr = lane & 15, quad = lane >> 4;
  const int bh = blockIdx.y;
  const int b = bh / H, h = bh % H;
  const int q0 = blockIdx.x * 128;
  const u16* vt_base = VT + (size_t)bh * 64 * S;
  const float SC = 0.125f * 1.44269504089f;   // 1/sqrt(dk) * log2(e)

  // Q fragments (MFMA B-operand), 2 per wave: q = q0 + wid*32 + f*16 + lr
  bf16x8 qf[2][2];
  #pragma unroll
  for (int f = 0; f < 2; ++f) {
    int qm = q0 + wid * 32 + f * 16 + lr;
    const u16* qptr = Qp + (size_t)(b * S + qm) * QSTR + h * 64;
    qf[f][0] = *(const bf16x8*)(qptr + quad * 8);
    qf[f][1] = *(const bf16x8*)(qptr + 32 + quad * 8);
  }

  float m_i[2] = {-1e30f, -1e30f}, l_i[2] = {0.f, 0.f};
  float O[2][4][4];
  #pragma unroll
  for (int f = 0; f < 2; ++f)
    #pragma unroll
    for (int nt = 0; nt < 4; ++nt)
      #pragma unroll
      for (int i = 0; i < 4; ++i) O[f][nt][i] = 0.f;

  u16* pw = &p_lds[wid * 32 * 72];

  for (int kt = 0; kt < S; kt += 64) {
    #pragma unroll
    for (int it = 0; it < 2; ++it) {
      int c = tid + it * 256;
      int r = c >> 3;
      int cc = (c & 7) * 8;
      uint4 kv = *(const uint4*)(Kp + (size_t)(b * S + kt + r) * QSTR + h * 64 + cc);
      *(uint4*)(&kt_lds[r * 72 + cc]) = kv;
      uint4 vv = *(const uint4*)(vt_base + (size_t)r * S + kt + cc);
      *(uint4*)(&vt_lds[r * 72 + cc]) = vv;
    }
    if (tid < 64) msk_lds[tid] = mask[b * S + kt + tid] ? 0.f : -1e30f;
    __syncthreads();

    // S^T (log2-domain): col(lane&15)=q, row(quad*4+i)=k-pos; kf shared by both f
    float s[2][4][4];
    #pragma unroll
    for (int st = 0; st < 4; ++st) {
      bf16x8 kf0 = *(const bf16x8*)(&kt_lds[(st * 16 + lr) * 72 + quad * 8]);
      bf16x8 kf1 = *(const bf16x8*)(&kt_lds[(st * 16 + lr) * 72 + 32 + quad * 8]);
      float4 mv = *(const float4*)(&msk_lds[st * 16 + quad * 4]);
      #pragma unroll
      for (int f = 0; f < 2; ++f) {
        f32x4 c = {0.f, 0.f, 0.f, 0.f};
        c = __builtin_amdgcn_mfma_f32_16x16x32_bf16(kf0, qf[f][0], c, 0, 0, 0);
        c = __builtin_amdgcn_mfma_f32_16x16x32_bf16(kf1, qf[f][1], c, 0, 0, 0);
        s[f][st][0] = c[0] * SC + mv.x;
        s[f][st][1] = c[1] * SC + mv.y;
        s[f][st][2] = c[2] * SC + mv.z;
        s[f][st][3] = c[3] * SC + mv.w;
      }
    }

    // online softmax per fragment (per-lane scalar state, 2 shfls each)
    float al[2];
    #pragma unroll
    for (int f = 0; f < 2; ++f) {
      float tmax = s[f][0][0];
      #pragma unroll
      for (int st = 0; st < 4; ++st)
        #pragma unroll
        for (int i = 0; i < 4; ++i) tmax = fmaxf(tmax, s[f][st][i]);
      tmax = fmaxf(tmax, __shfl_xor(tmax, 16, 64));
      tmax = fmaxf(tmax, __shfl_xor(tmax, 32, 64));
      float mn = fmaxf(m_i[f], tmax);
      al[f] = exp2f(m_i[f] - mn);
      m_i[f] = mn;
      float rs = 0.f;
      #pragma unroll
      for (int st = 0; st < 4; ++st)
        #pragma unroll
        for (int i = 0; i < 4; ++i) {
          float p = exp2f(s[f][st][i] - mn);
          s[f][st][i] = p; rs += p;
        }
      rs += __shfl_xor(rs, 16, 64);
      rs += __shfl_xor(rs, 32, 64);
      l_i[f] = l_i[f] * al[f] + rs;
    }

    // P -> LDS: per st one ds_write_b64 (two packed dwords)
    #pragma unroll
    for (int f = 0; f < 2; ++f) {
      #pragma unroll
      for (int st = 0; st < 4; ++st) {
        uint2 pk;
        pk.x = pack2bf(s[f][st][0], s[f][st][1]);
        pk.y = pack2bf(s[f][st][2], s[f][st][3]);
        *(uint2*)(&pw[(f * 16 + lr) * 72 + st * 16 + quad * 4]) = pk;
      }
    }

    // O^T += (P@V)^T: vf shared across f; pf hoisted per f
    bf16x8 pf[2][2];
    #pragma unroll
    for (int f = 0; f < 2; ++f) {
      pf[f][0] = *(const bf16x8*)(&pw[(f * 16 + lr) * 72 + quad * 8]);
      pf[f][1] = *(const bf16x8*)(&pw[(f * 16 + lr) * 72 + 32 + quad * 8]);
    }
    #pragma unroll
    for (int nt = 0; nt < 4; ++nt) {
      bf16x8 vf0 = *(const bf16x8*)(&vt_lds[(nt * 16 + lr) * 72 + quad * 8]);
      bf16x8 vf1 = *(const bf16x8*)(&vt_lds[(nt * 16 + lr) * 72 + 32 + quad * 8]);
      #pragma unroll
      for (int f = 0; f < 2; ++f) {
        f32x4 c;
        c[0] = O[f][nt][0] * al[f]; c[1] = O[f][nt][1] * al[f];
        c[2] = O[f][nt][2] * al[f]; c[3] = O[f][nt][3] * al[f];
        c = __builtin_amdgcn_mfma_f32_16x16x32_bf16(vf0, pf[f][0], c, 0, 0, 0);
        c = __builtin_amdgcn_mfma_f32_16x16x32_bf16(vf1, pf[f][1], c, 0, 0, 0);
        O[f][nt][0] = c[0]; O[f][nt][1] = c[1]; O[f][nt][2] = c[2]; O[f][nt][3] = c[3];
      }
    }
    __syncthreads();
  }

  // epilogue: q = q0 + wid*32 + f*16 + lr; d = nt*16 + quad*4 + i
  #pragma unroll
  for (int f = 0; f < 2; ++f) {
    float linv = 1.f / fmaxf(l_i[f], 1e-30f);
    int q = q0 + wid * 32 + f * 16 + lr;
    u16* op = ctx + (size_t)(b * S + q) * (H * 64) + h * 64;
    #pragma unroll
    for (int nt = 0; nt < 4; ++nt) {
      u16x4 o;
      o.x = f2bf(O[f][nt][0] * linv); o.y = f2bf(O[f][nt][1] * linv);
      o.z = f2bf(O[f][nt][2] * linv); o.w = f2bf(O[f][nt][3] * linv);
      *(u16x4*)(op + nt * 16 + quad * 4) = o;
    }
  }
}

// ---------------- fused residual add + LayerNorm (vectorized) ----------------
__device__ inline float block_reduce_sum(float v, float* sbuf) {
  #pragma unroll
  for (int m = 1; m < 64; m <<= 1) v += __shfl_xor(v, m, 64);
  int w = threadIdx.x >> 6;
  if ((threadIdx.x & 63) == 0) sbuf[w] = v;
  __syncthreads();
  v = sbuf[0] + sbuf[1] + sbuf[2] + sbuf[3];
  __syncthreads();
  return v;
}

__global__ __launch_bounds__(256) void add_ln(const float* __restrict__ a32,
                                              const u16* __restrict__ a16,
                                              const u16* __restrict__ b,
                                              const float* __restrict__ g,
                                              const float* __restrict__ be,
                                              u16* __restrict__ out16,
                                              float* __restrict__ out32, int D) {
  __shared__ float sbuf[4];
  int row = blockIdx.x;
  size_t base = (size_t)row * D;
  int i = threadIdx.x * 4;
  float v[4];
  {
    u16x4 bv = *(const u16x4*)(b + base + i);
    if (a32) {
      float4 av = *(const float4*)(a32 + base + i);
      v[0] = av.x + bf2f(bv.x); v[1] = av.y + bf2f(bv.y);
      v[2] = av.z + bf2f(bv.z); v[3] = av.w + bf2f(bv.w);
    } else {
      u16x4 av = *(const u16x4*)(a16 + base + i);
      v[0] = bf2f(av.x) + bf2f(bv.x); v[1] = bf2f(av.y) + bf2f(bv.y);
      v[2] = bf2f(av.z) + bf2f(bv.z); v[3] = bf2f(av.w) + bf2f(bv.w);
    }
  }
  float sum = v[0] + v[1] + v[2] + v[3];
  sum = block_reduce_sum(sum, sbuf);
  float mean = sum / (float)D;
  float var = 0.f;
  #pragma unroll
  for (int j = 0; j < 4; ++j) { float d = v[j] - mean; var += d * d; }
  var = block_reduce_sum(var, sbuf);
  float rstd = rsqrtf(var / (float)D + 1e-5f);
  float4 gv = *(const float4*)(g + i);
  float4 bev = *(const float4*)(be + i);
  float o0 = (v[0] - mean) * rstd * gv.x + bev.x;
  float o1 = (v[1] - mean) * rstd * gv.y + bev.y;
  float o2 = (v[2] - mean) * rstd * gv.z + bev.z;
  float o3 = (v[3] - mean) * rstd * gv.w + bev.w;
  if (out32) {
    float4 o = {o0, o1, o2, o3};
    *(float4*)(out32 + base + i) = o;
  } else {
    u16x4 o;
    o.x = f2bf(o0); o.y = f2bf(o1); o.z = f2bf(o2); o.w = f2bf(o3);
    *(u16x4*)(out16 + base + i) = o;
  }
}

// ---------------- launch ----------------
extern "C" void kernel_launch(void* const* d_in, const int* in_sizes, int n_in,
                              void* d_out, int out_size, void* d_ws, size_t ws_size,
                              hipStream_t stream) {
  (void)in_sizes; (void)n_in; (void)out_size; (void)ws_size;
  const float* x   = (const float*)d_in[0];
  const int* mask  = (const int*)d_in[1];
  const float* wq  = (const float*)d_in[2];
  const float* bq  = (const float*)d_in[3];
  const float* wk  = (const float*)d_in[4];
  const float* bk  = (const float*)d_in[5];
  const float* wv  = (const float*)d_in[6];
  const float* bv  = (const float*)d_in[7];
  const float* wo  = (const float*)d_in[8];
  const float* bo  = (const float*)d_in[9];
  const float* w1  = (const float*)d_in[10];
  const float* b1  = (const float*)d_in[11];
  const float* w2  = (const float*)d_in[12];
  const float* b2  = (const float*)d_in[13];
  const float* g1  = (const float*)d_in[14];
  const float* be1 = (const float*)d_in[15];
  const float* g2  = (const float*)d_in[16];
  const float* be2 = (const float*)d_in[17];

  const int B = 4, S = 2048, D = 1024, H = 16, DFF = 4096;
  const int D3 = 3 * D;
  const size_t TOK = (size_t)B * S;
  const size_t TD = TOK * D;

  u16* ws   = (u16*)d_ws;
  u16* QKVp = ws;                          // [0, 3*TD)
  u16* xb   = ws + 3 * TD;                 // dead after QKV gemm
  u16* VT   = xb;
  u16* CTX  = ws + 4 * TD;
  u16* ATT  = ws + 5 * TD;
  u16* Hb   = ws + 6 * TD;
  u16* QKVT = ws + 7 * TD;                 // 3*D*D
  u16* WOT  = QKVT + 3 * (size_t)D * D;    // D*D
  u16* W1T  = WOT + (size_t)D * D;         // D*DFF
  u16* FF1  = ws;                          // overlays QKVp+VT
  u16* FF2  = ATT;
  u16* W2T  = QKVT;                        // into dead QKVT+WOT
  float* biasc = (float*)CTX;              // dead before flash writes CTX

  dim3 blk(256);

  cvt_bf16<<<dim3((unsigned)(TD / (256 * 4))), blk, 0, stream>>>(x, xb, (int)TD);
  concat3<<<dim3(4), blk, 0, stream>>>(bq, bk, bv, biasc, D);

  transpose_f32_bf16<<<dim3(D / 32, D / 32), blk, 0, stream>>>(wq, QKVT, D, D);
  transpose_f32_bf16<<<dim3(D / 32, D / 32), blk, 0, stream>>>(wk, QKVT + (size_t)D * D, D, D);
  transpose_f32_bf16<<<dim3(D / 32, D / 32), blk, 0, stream>>>(wv, QKVT + 2 * (size_t)D * D, D, D);
  transpose_f32_bf16<<<dim3(D / 32, D / 32), blk, 0, stream>>>(wo, WOT, D, D);
  transpose_f32_bf16<<<dim3(DFF / 32, D / 32), blk, 0, stream>>>(w1, W1T, D, DFF);

  gemm_bt<<<dim3(D3 / 128, TOK / 128), blk, 0, stream>>>(xb, QKVT, biasc, QKVp, (int)TOK, D3, D, 0);

  transpose_v<<<dim3(S / 32, 2, B * H), blk, 0, stream>>>(QKVp, VT, B, S, H, D3, 2 * D);

  flash_attn<<<dim3(S / 128, B * H), blk, 0, stream>>>(QKVp, QKVp + D, VT, mask, CTX, B, S, H, D3);

  gemm_bt<<<dim3(D / 128, TOK / 128), blk, 0, stream>>>(CTX, WOT, bo, ATT, (int)TOK, D, D, 0);

  transpose_f32_bf16<<<dim3(D / 32, DFF / 32), blk, 0, stream>>>(w2, W2T, DFF, D);

  add_ln<<<dim3((unsigned)TOK), blk, 0, stream>>>(x, (const u16*)nullptr, ATT, g1, be1,
                                                  Hb, (float*)nullptr, D);

  gemm_bt<<<dim3(DFF / 128, TOK / 128), blk, 0, stream>>>(Hb, W1T, b1, FF1, (int)TOK, DFF, D, 1);
  gemm_bt<<<dim3(D / 128, TOK / 128), blk, 0, stream>>>(FF1, W2T, b2, FF2, (int)TOK, D, DFF, 0);

  add_ln<<<dim3((unsigned)TOK), blk, 0, stream>>>((const float*)nullptr, Hb, FF2, g2, be2,
                                                  (u16*)nullptr, (float*)d_out, D);
}

// Round 7
// 664.314 us; speedup vs baseline: 1.0870x; 1.0870x over previous
//
#include <hip/hip_runtime.h>

typedef unsigned short u16;
typedef __attribute__((ext_vector_type(4))) unsigned short u16x4;
typedef __attribute__((ext_vector_type(8))) short bf16x8;
typedef __attribute__((ext_vector_type(4))) float f32x4;

__device__ inline float bf2f(u16 u) {
  union { unsigned int i; float f; } v; v.i = ((unsigned int)u) << 16; return v.f;
}
__device__ inline u16 f2bf(float f) {
  union { float f; unsigned int i; } v; v.f = f;
  unsigned int r = v.i + 0x7fffu + ((v.i >> 16) & 1u);
  return (u16)(r >> 16);
}
// pack two f32 -> two bf16 in one u32 (round-half-up via +0x8000, then byte-perm)
__device__ inline unsigned int pack2bf(float lo, float hi) {
  union { float f; unsigned int i; } a, b; a.f = lo; b.f = hi;
  return __builtin_amdgcn_perm(b.i + 0x8000u, a.i + 0x8000u, 0x07060302u);
}

// async global->LDS, 16B per lane; LDS dest = wave-uniform base + lane*16 (m97/m104)
typedef const __attribute__((address_space(1))) unsigned int* gas_t;
typedef __attribute__((address_space(3))) unsigned int* las_t;
__device__ inline void gload_lds16(const u16* g, u16* l) {
  __builtin_amdgcn_global_load_lds((gas_t)(unsigned long long)(const void*)g,
                                   (las_t)(unsigned int)(unsigned long long)(void*)l,
                                   16, 0, 0);
}

// ---------------- fp32 -> bf16 convert (x) ----------------
__global__ __launch_bounds__(256) void cvt_bf16(const float* __restrict__ src,
                                                u16* __restrict__ dst, int n) {
  int i = (blockIdx.x * 256 + threadIdx.x) * 4;
  if (i >= n) return;
  float4 v = *(const float4*)(src + i);
  u16x4 o;
  o.x = f2bf(v.x); o.y = f2bf(v.y); o.z = f2bf(v.z); o.w = f2bf(v.w);
  *(u16x4*)(dst + i) = o;
}

// ---------------- bias concat (fp32): [bq|bk|bv] -> o[3n] ----------------
__global__ __launch_bounds__(256) void concat3(const float* __restrict__ a,
                                               const float* __restrict__ b,
                                               const float* __restrict__ c,
                                               float* __restrict__ o, int n) {
  int i = blockIdx.x * 256 + threadIdx.x;
  if (i >= n) return;
  o[i] = a[i]; o[n + i] = b[i]; o[2 * n + i] = c[i];
}

// ------------- transpose+convert: fp32 src [R][C] -> bf16 dst [C][R] -------
__global__ __launch_bounds__(256) void transpose_f32_bf16(const float* __restrict__ src,
                                                          u16* __restrict__ dst,
                                                          int R, int C) {
  __shared__ u16 tile[32][33];
  int tx = threadIdx.x & 31, ty = threadIdx.x >> 5;  // 32 x 8
  int c0 = blockIdx.x * 32, r0 = blockIdx.y * 32;
  #pragma unroll
  for (int i = ty; i < 32; i += 8)
    tile[i][tx] = f2bf(src[(size_t)(r0 + i) * C + c0 + tx]);
  __syncthreads();
  #pragma unroll
  for (int i = ty; i < 32; i += 8)
    dst[(size_t)(c0 + i) * R + r0 + tx] = tile[tx][i];
}

// ---- per-head V transpose from packed QKV: src row-stride RS, col offset CO ----
__global__ __launch_bounds__(256) void transpose_v(const u16* __restrict__ src,
                                                   u16* __restrict__ VT,
                                                   int B, int S, int H, int RS, int CO) {
  __shared__ u16 tile[32][33];
  int tx = threadIdx.x & 31, ty = threadIdx.x >> 5;
  int s0 = blockIdx.x * 32, d0 = blockIdx.y * 32;
  int bh = blockIdx.z;
  int b = bh / H, h = bh % H;
  #pragma unroll
  for (int i = ty; i < 32; i += 8)
    tile[i][tx] = src[(size_t)(b * S + s0 + i) * RS + CO + h * 64 + d0 + tx];
  __syncthreads();
  #pragma unroll
  for (int i = ty; i < 32; i += 8)
    VT[((size_t)bh * 64 + d0 + i) * S + s0 + tx] = tile[tx][i];
}

// ---------------- GEMM: C[M,N] = A[M,K] @ Bt[N,K]^T + bias, opt relu --------
__global__ __launch_bounds__(256) void gemm_bt(const u16* __restrict__ A,
                                               const u16* __restrict__ Bt,
                                               const float* __restrict__ bias,
                                               u16* __restrict__ C,
                                               int M, int N, int K, int relu) {
  __shared__ u16 As[128 * 32];
  __shared__ u16 Bs[128 * 32];
  const int tid = threadIdx.x;
  const int lane = tid & 63, wid = tid >> 6;
  const int lr = lane & 15, quad = lane >> 4;
  const int wm = (wid >> 1) * 64, wn = (wid & 1) * 64;
  const int m0 = blockIdx.y * 128, n0 = blockIdx.x * 128;
  const int lrow = lane >> 2;
  const int lcol = (lane & 3) * 8;

  f32x4 acc[4][4];
  const f32x4 zero = {0.f, 0.f, 0.f, 0.f};
  #pragma unroll
  for (int mt = 0; mt < 4; ++mt)
    #pragma unroll
    for (int nt = 0; nt < 4; ++nt) acc[mt][nt] = zero;

  for (int k0 = 0; k0 < K; k0 += 32) {
    #pragma unroll
    for (int it = 0; it < 2; ++it) {
      int rbase = wid * 32 + it * 16;
      gload_lds16(A + (size_t)(m0 + rbase + lrow) * K + k0 + lcol, &As[rbase * 32]);
      gload_lds16(Bt + (size_t)(n0 + rbase + lrow) * K + k0 + lcol, &Bs[rbase * 32]);
    }
    __syncthreads();
    bf16x8 af[4], bfr[4];
    #pragma unroll
    for (int mt = 0; mt < 4; ++mt)
      af[mt] = *(const bf16x8*)(&As[(wm + mt * 16 + lr) * 32 + quad * 8]);
    #pragma unroll
    for (int nt = 0; nt < 4; ++nt)
      bfr[nt] = *(const bf16x8*)(&Bs[(wn + nt * 16 + lr) * 32 + quad * 8]);
    #pragma unroll
    for (int mt = 0; mt < 4; ++mt)
      #pragma unroll
      for (int nt = 0; nt < 4; ++nt)
        acc[mt][nt] = __builtin_amdgcn_mfma_f32_16x16x32_bf16(af[mt], bfr[nt], acc[mt][nt], 0, 0, 0);
    __syncthreads();
  }

  #pragma unroll
  for (int nt = 0; nt < 4; ++nt) {
    int n = n0 + wn + nt * 16 + lr;
    float bv = bias[n];
    #pragma unroll
    for (int mt = 0; mt < 4; ++mt) {
      #pragma unroll
      for (int i = 0; i < 4; ++i) {
        int m = m0 + wm + mt * 16 + quad * 4 + i;
        float v = acc[mt][nt][i] + bv;
        if (relu) v = fmaxf(v, 0.f);
        C[(size_t)m * N + n] = f2bf(v);
      }
    }
  }
}

// ---------------- flash attention (S^T, 16 q-rows per wave) ----------------
// grid: (S/64, B*H); block 256 (4 waves). Round-5 geometry (occupancy ~44%)
// + exp2 domain + v_perm P-pack + hoisted pf reads.
__global__ __launch_bounds__(256) void flash_attn(const u16* __restrict__ Qp,
                                                  const u16* __restrict__ Kp,
                                                  const u16* __restrict__ VT,
                                                  const int* __restrict__ mask,
                                                  u16* __restrict__ ctx,
                                                  int B, int S, int H, int QSTR) {
  __shared__ u16 kt_lds[64 * 72];        // K tile [krow][dk], stride 72
  __shared__ u16 vt_lds[64 * 72];        // V^T tile [dk][krow], stride 72
  __shared__ u16 p_lds[4 * 16 * 72];     // per-wave P [q][k], stride 72
  __shared__ float msk_lds[64];
  const int tid = threadIdx.x;
  const int lane = tid & 63, wid = tid >> 6;
  const int lr = lane & 15, quad = lane >> 4;
  const int bh = blockIdx.y;
  const int b = bh / H, h = bh % H;
  const int q0 = blockIdx.x * 64;
  const u16* vt_base = VT + (size_t)bh * 64 * S;
  const float SC = 0.125f * 1.44269504089f;   // 1/sqrt(dk) * log2(e)

  // Q fragments (MFMA B-operand: B[n=q=lane&15][k=quad*8+j])
  bf16x8 qf[2];
  {
    int qm = q0 + wid * 16 + lr;
    const u16* qptr = Qp + (size_t)(b * S + qm) * QSTR + h * 64;
    qf[0] = *(const bf16x8*)(qptr + quad * 8);
    qf[1] = *(const bf16x8*)(qptr + 32 + quad * 8);
  }

  float m_i = -1e30f, l_i = 0.f;
  float O[4][4];   // O^T regs: [nt][i], d = nt*16 + quad*4 + i, q = lr
  #pragma unroll
  for (int nt = 0; nt < 4; ++nt)
    #pragma unroll
    for (int i = 0; i < 4; ++i) O[nt][i] = 0.f;

  u16* pw = &p_lds[wid * 16 * 72];

  for (int kt = 0; kt < S; kt += 64) {
    #pragma unroll
    for (int it = 0; it < 2; ++it) {
      int c = tid + it * 256;
      int r = c >> 3;
      int cc = (c & 7) * 8;
      uint4 kv = *(const uint4*)(Kp + (size_t)(b * S + kt + r) * QSTR + h * 64 + cc);
      *(uint4*)(&kt_lds[r * 72 + cc]) = kv;
      uint4 vv = *(const uint4*)(vt_base + (size_t)r * S + kt + cc);
      *(uint4*)(&vt_lds[r * 72 + cc]) = vv;
    }
    if (tid < 64) msk_lds[tid] = mask[b * S + kt + tid] ? 0.f : -1e30f;
    __syncthreads();

    // S^T (log2 domain): col(lane&15)=q, row(quad*4+i)=k-pos
    float s[4][4];
    #pragma unroll
    for (int st = 0; st < 4; ++st) {
      f32x4 c = {0.f, 0.f, 0.f, 0.f};
      bf16x8 kf0 = *(const bf16x8*)(&kt_lds[(st * 16 + lr) * 72 + quad * 8]);
      bf16x8 kf1 = *(const bf16x8*)(&kt_lds[(st * 16 + lr) * 72 + 32 + quad * 8]);
      c = __builtin_amdgcn_mfma_f32_16x16x32_bf16(kf0, qf[0], c, 0, 0, 0);
      c = __builtin_amdgcn_mfma_f32_16x16x32_bf16(kf1, qf[1], c, 0, 0, 0);
      float4 mv = *(const float4*)(&msk_lds[st * 16 + quad * 4]);
      s[st][0] = c[0] * SC + mv.x;
      s[st][1] = c[1] * SC + mv.y;
      s[st][2] = c[2] * SC + mv.z;
      s[st][3] = c[3] * SC + mv.w;
    }

    // online softmax: per-lane scalar state, 2-shfl reductions
    float tmax = s[0][0];
    #pragma unroll
    for (int st = 0; st < 4; ++st)
      #pragma unroll
      for (int i = 0; i < 4; ++i) tmax = fmaxf(tmax, s[st][i]);
    tmax = fmaxf(tmax, __shfl_xor(tmax, 16, 64));
    tmax = fmaxf(tmax, __shfl_xor(tmax, 32, 64));
    float mn = fmaxf(m_i, tmax);
    float al = exp2f(m_i - mn);
    m_i = mn;
    float rs = 0.f;
    #pragma unroll
    for (int st = 0; st < 4; ++st)
      #pragma unroll
      for (int i = 0; i < 4; ++i) {
        float p = exp2f(s[st][i] - mn);
        s[st][i] = p; rs += p;
      }
    rs += __shfl_xor(rs, 16, 64);
    rs += __shfl_xor(rs, 32, 64);
    l_i = l_i * al + rs;

    // P[q][k] to LDS: one ds_write_b64 per st (two v_perm-packed dwords)
    #pragma unroll
    for (int st = 0; st < 4; ++st) {
      uint2 pk;
      pk.x = pack2bf(s[st][0], s[st][1]);
      pk.y = pack2bf(s[st][2], s[st][3]);
      *(uint2*)(&pw[lr * 72 + st * 16 + quad * 4]) = pk;
    }

    // O^T = al*O^T + (P@V)^T: pf hoisted (2 reads), vf per nt
    bf16x8 pf0 = *(const bf16x8*)(&pw[lr * 72 + quad * 8]);
    bf16x8 pf1 = *(const bf16x8*)(&pw[lr * 72 + 32 + quad * 8]);
    #pragma unroll
    for (int nt = 0; nt < 4; ++nt) {
      f32x4 c;
      c[0] = O[nt][0] * al; c[1] = O[nt][1] * al;
      c[2] = O[nt][2] * al; c[3] = O[nt][3] * al;
      bf16x8 vf0 = *(const bf16x8*)(&vt_lds[(nt * 16 + lr) * 72 + quad * 8]);
      bf16x8 vf1 = *(const bf16x8*)(&vt_lds[(nt * 16 + lr) * 72 + 32 + quad * 8]);
      c = __builtin_amdgcn_mfma_f32_16x16x32_bf16(vf0, pf0, c, 0, 0, 0);
      c = __builtin_amdgcn_mfma_f32_16x16x32_bf16(vf1, pf1, c, 0, 0, 0);
      O[nt][0] = c[0]; O[nt][1] = c[1]; O[nt][2] = c[2]; O[nt][3] = c[3];
    }
    __syncthreads();
  }

  // epilogue: lane lr = q-row; d = nt*16 + quad*4 + i -> vectorized 8B stores
  float linv = 1.f / fmaxf(l_i, 1e-30f);
  int q = q0 + wid * 16 + lr;
  u16* op = ctx + (size_t)(b * S + q) * (H * 64) + h * 64;
  #pragma unroll
  for (int nt = 0; nt < 4; ++nt) {
    u16x4 o;
    o.x = f2bf(O[nt][0] * linv); o.y = f2bf(O[nt][1] * linv);
    o.z = f2bf(O[nt][2] * linv); o.w = f2bf(O[nt][3] * linv);
    *(u16x4*)(op + nt * 16 + quad * 4) = o;
  }
}

// ---------------- fused residual add + LayerNorm (vectorized) ----------------
__device__ inline float block_reduce_sum(float v, float* sbuf) {
  #pragma unroll
  for (int m = 1; m < 64; m <<= 1) v += __shfl_xor(v, m, 64);
  int w = threadIdx.x >> 6;
  if ((threadIdx.x & 63) == 0) sbuf[w] = v;
  __syncthreads();
  v = sbuf[0] + sbuf[1] + sbuf[2] + sbuf[3];
  __syncthreads();
  return v;
}

__global__ __launch_bounds__(256) void add_ln(const float* __restrict__ a32,
                                              const u16* __restrict__ a16,
                                              const u16* __restrict__ b,
                                              const float* __restrict__ g,
                                              const float* __restrict__ be,
                                              u16* __restrict__ out16,
                                              float* __restrict__ out32, int D) {
  __shared__ float sbuf[4];
  int row = blockIdx.x;
  size_t base = (size_t)row * D;
  int i = threadIdx.x * 4;
  float v[4];
  {
    u16x4 bv = *(const u16x4*)(b + base + i);
    if (a32) {
      float4 av = *(const float4*)(a32 + base + i);
      v[0] = av.x + bf2f(bv.x); v[1] = av.y + bf2f(bv.y);
      v[2] = av.z + bf2f(bv.z); v[3] = av.w + bf2f(bv.w);
    } else {
      u16x4 av = *(const u16x4*)(a16 + base + i);
      v[0] = bf2f(av.x) + bf2f(bv.x); v[1] = bf2f(av.y) + bf2f(bv.y);
      v[2] = bf2f(av.z) + bf2f(bv.z); v[3] = bf2f(av.w) + bf2f(bv.w);
    }
  }
  float sum = v[0] + v[1] + v[2] + v[3];
  sum = block_reduce_sum(sum, sbuf);
  float mean = sum / (float)D;
  float var = 0.f;
  #pragma unroll
  for (int j = 0; j < 4; ++j) { float d = v[j] - mean; var += d * d; }
  var = block_reduce_sum(var, sbuf);
  float rstd = rsqrtf(var / (float)D + 1e-5f);
  float4 gv = *(const float4*)(g + i);
  float4 bev = *(const float4*)(be + i);
  float o0 = (v[0] - mean) * rstd * gv.x + bev.x;
  float o1 = (v[1] - mean) * rstd * gv.y + bev.y;
  float o2 = (v[2] - mean) * rstd * gv.z + bev.z;
  float o3 = (v[3] - mean) * rstd * gv.w + bev.w;
  if (out32) {
    float4 o = {o0, o1, o2, o3};
    *(float4*)(out32 + base + i) = o;
  } else {
    u16x4 o;
    o.x = f2bf(o0); o.y = f2bf(o1); o.z = f2bf(o2); o.w = f2bf(o3);
    *(u16x4*)(out16 + base + i) = o;
  }
}

// ---------------- launch ----------------
extern "C" void kernel_launch(void* const* d_in, const int* in_sizes, int n_in,
                              void* d_out, int out_size, void* d_ws, size_t ws_size,
                              hipStream_t stream) {
  (void)in_sizes; (void)n_in; (void)out_size; (void)ws_size;
  const float* x   = (const float*)d_in[0];
  const int* mask  = (const int*)d_in[1];
  const float* wq  = (const float*)d_in[2];
  const float* bq  = (const float*)d_in[3];
  const float* wk  = (const float*)d_in[4];
  const float* bk  = (const float*)d_in[5];
  const float* wv  = (const float*)d_in[6];
  const float* bv  = (const float*)d_in[7];
  const float* wo  = (const float*)d_in[8];
  const float* bo  = (const float*)d_in[9];
  const float* w1  = (const float*)d_in[10];
  const float* b1  = (const float*)d_in[11];
  const float* w2  = (const float*)d_in[12];
  const float* b2  = (const float*)d_in[13];
  const float* g1  = (const float*)d_in[14];
  const float* be1 = (const float*)d_in[15];
  const float* g2  = (const float*)d_in[16];
  const float* be2 = (const float*)d_in[17];

  const int B = 4, S = 2048, D = 1024, H = 16, DFF = 4096;
  const int D3 = 3 * D;
  const size_t TOK = (size_t)B * S;
  const size_t TD = TOK * D;

  u16* ws   = (u16*)d_ws;
  u16* QKVp = ws;                          // [0, 3*TD)
  u16* xb   = ws + 3 * TD;                 // dead after QKV gemm
  u16* VT   = xb;
  u16* CTX  = ws + 4 * TD;
  u16* ATT  = ws + 5 * TD;
  u16* Hb   = ws + 6 * TD;
  u16* QKVT = ws + 7 * TD;                 // 3*D*D
  u16* WOT  = QKVT + 3 * (size_t)D * D;    // D*D
  u16* W1T  = WOT + (size_t)D * D;         // D*DFF
  u16* FF1  = ws;                          // overlays QKVp+VT
  u16* FF2  = ATT;
  u16* W2T  = QKVT;                        // into dead QKVT+WOT
  float* biasc = (float*)CTX;              // dead before flash writes CTX

  dim3 blk(256);

  cvt_bf16<<<dim3((unsigned)(TD / (256 * 4))), blk, 0, stream>>>(x, xb, (int)TD);
  concat3<<<dim3(4), blk, 0, stream>>>(bq, bk, bv, biasc, D);

  transpose_f32_bf16<<<dim3(D / 32, D / 32), blk, 0, stream>>>(wq, QKVT, D, D);
  transpose_f32_bf16<<<dim3(D / 32, D / 32), blk, 0, stream>>>(wk, QKVT + (size_t)D * D, D, D);
  transpose_f32_bf16<<<dim3(D / 32, D / 32), blk, 0, stream>>>(wv, QKVT + 2 * (size_t)D * D, D, D);
  transpose_f32_bf16<<<dim3(D / 32, D / 32), blk, 0, stream>>>(wo, WOT, D, D);
  transpose_f32_bf16<<<dim3(DFF / 32, D / 32), blk, 0, stream>>>(w1, W1T, D, DFF);

  gemm_bt<<<dim3(D3 / 128, TOK / 128), blk, 0, stream>>>(xb, QKVT, biasc, QKVp, (int)TOK, D3, D, 0);

  transpose_v<<<dim3(S / 32, 2, B * H), blk, 0, stream>>>(QKVp, VT, B, S, H, D3, 2 * D);

  flash_attn<<<dim3(S / 64, B * H), blk, 0, stream>>>(QKVp, QKVp + D, VT, mask, CTX, B, S, H, D3);

  gemm_bt<<<dim3(D / 128, TOK / 128), blk, 0, stream>>>(CTX, WOT, bo, ATT, (int)TOK, D, D, 0);

  transpose_f32_bf16<<<dim3(D / 32, DFF / 32), blk, 0, stream>>>(w2, W2T, DFF, D);

  add_ln<<<dim3((unsigned)TOK), blk, 0, stream>>>(x, (const u16*)nullptr, ATT, g1, be1,
                                                  Hb, (float*)nullptr, D);

  gemm_bt<<<dim3(DFF / 128, TOK / 128), blk, 0, stream>>>(Hb, W1T, b1, FF1, (int)TOK, DFF, D, 1);
  gemm_bt<<<dim3(D / 128, TOK / 128), blk, 0, stream>>>(FF1, W2T, b2, FF2, (int)TOK, D, DFF, 0);

  add_ln<<<dim3((unsigned)TOK), blk, 0, stream>>>((const float*)nullptr, Hb, FF2, g2, be2,
                                                  (u16*)nullptr, (float*)d_out, D);
}